// Round 1
// baseline (696.566 us; speedup 1.0000x reference)
//
#include <hip/hip_runtime.h>

typedef __attribute__((ext_vector_type(4))) float f4;
typedef __attribute__((ext_vector_type(4))) float f32x4;
typedef __attribute__((ext_vector_type(8))) short short8;
typedef __attribute__((ext_vector_type(4))) short short4v;
typedef __attribute__((ext_vector_type(4))) unsigned int uint4v;

#define S_  4096
#define NB_ 16
#define SLOPE_SCALE 0.838719677419355f

__device__ __forceinline__ float slope_for_head(int h) {
    return exp2f(-(float)(h + 1) * 0.125f) * SLOPE_SCALE;
}

// fp32 -> bf16 round-to-nearest-even
__device__ __forceinline__ short f2bf(float f) {
    unsigned u = __float_as_uint(f);
    u += 0x7FFFu + ((u >> 16) & 1u);
    return (short)(u >> 16);
}
__device__ __forceinline__ float bf2f(short s) {
    return __uint_as_float(((unsigned)(unsigned short)s) << 16);
}

// ---------------------------------------------------------------------------
// Phase 1 (MFMA): per-(bh, j): KVT[e][d] = sum_n v[n][e]*kd[n]*k[n][d]
// via bf16 hi/lo split: A=V^T(masked) hi/lo, B=(kd*K) hi/lo,
// C += Ahi*Bhi + Ahi*Blo + Alo*Bhi  (fp32-grade accuracy, matrix-core rate).
// Also writes:
//   vt  : masked V^T bf16, chunk-tiled [bh][j][c32(8)][e(64)][n32(32)]
//   kbf : bf16 k, row-major (phase3 S^T operand) — only when USE_KBF
// ---------------------------------------------------------------------------
template<int USE_KBF>
__global__ __launch_bounds__(256, 4) void phase1_kvblocks(
    const float* __restrict__ k, const float* __restrict__ v,
    const int* __restrict__ mask, float* __restrict__ kvt,
    short* __restrict__ vt, short* __restrict__ kbf)
{
    __shared__ float ks[64][69];   // kd-scaled k  (stride 69: frag reads <=2-way)
    __shared__ float vs[64][69];   // masked v
    const int j  = blockIdx.x;     // 0..15
    const int bh = blockIdx.y;     // 0..127
    const int b  = bh >> 6;
    const int h  = bh & 63;
    const int t  = threadIdx.x;
    const int wave = t >> 6, lane = t & 63, quad = lane >> 4, l16 = lane & 15;
    const float slope = slope_for_head(h);

    const f32x4 zf = {0.f, 0.f, 0.f, 0.f};
    f32x4 acc[4];                  // wave owns et=wave; dt=0..3
    acc[0] = zf; acc[1] = zf; acc[2] = zf; acc[3] = zf;

    const long long tilebase = ((long long)bh * S_ + j * 256) * 64;
    const long long vtbase   = ((long long)(bh * NB_ + j)) * 16384;

    for (int c = 0; c < 4; ++c) {
        // ---- stage 64 rows of (kd*k) and masked v; emit kbf on the fly ----
        for (int i = 0; i < 4; ++i) {
            int fi  = t + i * 256;       // 0..1023
            int row = fi >> 4;           // 0..63
            int col = (fi & 15) << 2;    // 0..60
            long long g = tilebase + (long long)(c * 64 + row) * 64 + col;
            f4 kk = *(const f4*)(k + g);
            if (USE_KBF) {
                short4v kb = { f2bf(kk.x), f2bf(kk.y), f2bf(kk.z), f2bf(kk.w) };
                *(short4v*)(kbf + g) = kb;
            }
            float kd = __expf(-slope * (float)(255 - (c * 64 + row)));
            *(f4*)&ks[row][col] = kk * kd;
            f4 vv = *(const f4*)(v + g);
            float mv = (float)mask[b * S_ + j * 256 + c * 64 + row];
            *(f4*)&vs[row][col] = vv * mv;
        }
        __syncthreads();

        // ---- V^T bf16 write (tiled layout) ----
        {
            int e  = t >> 2;             // 0..63
            int nb = (t & 3) << 4;       // 0,16,32,48 (n local to this 64-stage)
            unsigned w[8];
            #pragma unroll
            for (int i2 = 0; i2 < 8; ++i2) {
                unsigned lo = (unsigned short)f2bf(vs[nb + 2 * i2][e]);
                unsigned hi = (unsigned short)f2bf(vs[nb + 2 * i2 + 1][e]);
                w[i2] = lo | (hi << 16);
            }
            long long g = vtbase + (long long)(c * 2 + (nb >> 5)) * 2048
                        + e * 32 + (nb & 31);
            uint4v* dst = (uint4v*)(vt + g);
            uint4v w0 = {w[0], w[1], w[2], w[3]};
            uint4v w1 = {w[4], w[5], w[6], w[7]};
            dst[0] = w0; dst[1] = w1;
        }

        // ---- MFMA over the 2 K=32 chunks of this stage ----
        #pragma unroll
        for (int cc = 0; cc < 2; ++cc) {
            const int nb32 = cc * 32;
            // A-frag (V^T): A[e = wave*16+l16][n = nb32+quad*8+jj], hi/lo
            short8 ahi, alo;
            #pragma unroll
            for (int jj = 0; jj < 8; ++jj) {
                float x = vs[nb32 + quad * 8 + jj][wave * 16 + l16];
                short hi = f2bf(x);
                ahi[jj] = hi;
                alo[jj] = f2bf(x - bf2f(hi));
            }
            #pragma unroll
            for (int dt = 0; dt < 4; ++dt) {
                // B-frag (kd*K): B[n][d = dt*16+l16], hi/lo
                short8 bhi, blo;
                #pragma unroll
                for (int jj = 0; jj < 8; ++jj) {
                    float x = ks[nb32 + quad * 8 + jj][dt * 16 + l16];
                    short hi = f2bf(x);
                    bhi[jj] = hi;
                    blo[jj] = f2bf(x - bf2f(hi));
                }
                acc[dt] = __builtin_amdgcn_mfma_f32_16x16x32_bf16(ahi, bhi, acc[dt], 0, 0, 0);
                acc[dt] = __builtin_amdgcn_mfma_f32_16x16x32_bf16(ahi, blo, acc[dt], 0, 0, 0);
                acc[dt] = __builtin_amdgcn_mfma_f32_16x16x32_bf16(alo, bhi, acc[dt], 0, 0, 0);
            }
        }
        __syncthreads();
    }

    // C frag: e = wave*16 + quad*4 + reg, d = dt*16 + l16
    float* o = kvt + ((long long)(bh * NB_ + j)) * 4096;
    #pragma unroll
    for (int dt = 0; dt < 4; ++dt) {
        #pragma unroll
        for (int r = 0; r < 4; ++r) {
            int e = wave * 16 + quad * 4 + r;
            o[e * 64 + dt * 16 + l16] = acc[dt][r];
        }
    }
}

// ---------------------------------------------------------------------------
// Phase 2: prefix scan over j. 512 blocks (bh x quarter); each thread loads
// all 16 tiles up-front (independent loads -> one latency round), scans in
// registers, stores coalesced.
// ---------------------------------------------------------------------------
__global__ __launch_bounds__(256) void phase2_scan(float* __restrict__ kvt)
{
    const int g    = blockIdx.x;      // 0..511
    const int bh   = g >> 2;
    const int part = g & 3;
    const int h    = bh & 63;
    const float slope = slope_for_head(h);
    const float bd = __expf(-slope * 256.0f);

    f4* base = (f4*)(kvt + (long long)bh * NB_ * 4096) + part * 256 + threadIdx.x;
    f4 vals[NB_];
    #pragma unroll
    for (int jj = 0; jj < NB_; ++jj) vals[jj] = base[jj * 1024];
    f4 st = {0.f, 0.f, 0.f, 0.f};
    #pragma unroll
    for (int jj = 0; jj < NB_; ++jj) {
        base[jj * 1024] = st;         // S_j enters block j
        st = st * bd + vals[jj];
    }
}

// ---------------------------------------------------------------------------
// Phase 3: SINGLE-WAVE workgroups (64 thr). grid.x = j*4 + role, grid.y = bh.
// Each wave owns 64 m-rows (mwbase = role*64): no block-slot held by the
// causal 2/4/6/8-chunk imbalance — scheduler packs waves freely.
// kf comes pre-converted from kbf (bf16) when USE_KBF; vt reads are tiled
// (contiguous 1 KB per instruction). Math identical to the proven kernel.
// ---------------------------------------------------------------------------
template<int USE_KBF>
__global__ __launch_bounds__(64, 4) void phase3_output(
    const float* __restrict__ q, const float* __restrict__ kfp,
    const short* __restrict__ kbf, const float* __restrict__ kvt,
    const short* __restrict__ vt, float* __restrict__ out)
{
    __shared__ short P[64 * 56];      // [64 m][56 stride, 32 n used]
    const int role = blockIdx.x & 3;
    const int j    = blockIdx.x >> 2; // 0..15
    const int bh   = blockIdx.y;      // 0..127
    const int h    = bh & 63;
    const int lane = threadIdx.x;     // 0..63
    const int quad = lane >> 4;
    const int l16  = lane & 15;
    const float slope = slope_for_head(h);
    const int mwbase = role << 6;

    const long long rowbase = (long long)bh * S_ + j * 256 + mwbase;

    // ---- Q fragments (B-operand layout: B[k=ks*32+quad*8+jj][m=l16]) ----
    short8 qf[4][2];
    #pragma unroll
    for (int mt = 0; mt < 4; ++mt) {
        const float* qp = q + (rowbase + mt * 16 + l16) * 64 + quad * 8;
        #pragma unroll
        for (int ks = 0; ks < 2; ++ks) {
            f4 a = *(const f4*)(qp + ks * 32);
            f4 b = *(const f4*)(qp + ks * 32 + 4);
            short8 f;
            f[0] = f2bf(a.x); f[1] = f2bf(a.y); f[2] = f2bf(a.z); f[3] = f2bf(a.w);
            f[4] = f2bf(b.x); f[5] = f2bf(b.y); f[6] = f2bf(b.z); f[7] = f2bf(b.w);
            qf[mt][ks] = f;
        }
    }

    const f32x4 zf = {0.f, 0.f, 0.f, 0.f};
    f32x4 of[4][4];
    #pragma unroll
    for (int et = 0; et < 4; ++et)
        #pragma unroll
        for (int mt = 0; mt < 4; ++mt) of[et][mt] = zf;

    // ---- inter-block: O^T += kvT @ Q^T ----
    const float* kvp = kvt + ((long long)(bh * NB_ + j) << 12);
    #pragma unroll
    for (int et = 0; et < 4; ++et) {
        #pragma unroll
        for (int ks = 0; ks < 2; ++ks) {
            const float* p = kvp + (et * 16 + l16) * 64 + ks * 32 + quad * 8;
            f4 a = *(const f4*)(p);
            f4 b = *(const f4*)(p + 4);
            short8 af;
            af[0] = f2bf(a.x); af[1] = f2bf(a.y); af[2] = f2bf(a.z); af[3] = f2bf(a.w);
            af[4] = f2bf(b.x); af[5] = f2bf(b.y); af[6] = f2bf(b.z); af[7] = f2bf(b.w);
            #pragma unroll
            for (int mt = 0; mt < 4; ++mt)
                of[et][mt] = __builtin_amdgcn_mfma_f32_16x16x32_bf16(
                    af, qf[mt][ks], of[et][mt], 0, 0, 0);
        }
    }
    #pragma unroll
    for (int mt = 0; mt < 4; ++mt) {
        float qd = __expf(-slope * (float)(mwbase + mt * 16 + l16 + 1));
        #pragma unroll
        for (int et = 0; et < 4; ++et) of[et][mt] *= qd;
    }

    // ---- intra-block, causal, chunks of 32 n ----
    const float er1 = __expf(slope);
    const float er2 = er1 * er1;
    const float er3 = er2 * er1;
    const int nchunks = (mwbase >> 5) + 2;   // covers n < mwbase + 64
    const long long kTile = ((long long)bh * S_ + j * 256) * 64;
    const long long vTile = ((long long)(bh * NB_ + j)) * 16384;

    for (int c = 0; c < nchunks; ++c) {
        const int nbase = c << 5;

        // V^T A-fragments from tiled bf16 (contiguous 1KB per et)
        short8 va[4];
        #pragma unroll
        for (int et = 0; et < 4; ++et)
            va[et] = *(const short8*)(vt + vTile + c * 2048
                                      + (et * 16 + l16) * 32 + quad * 8);

        // K A-fragments (A[n=l16][k=ks*32+quad*8+jj])
        short8 kf[2][2];
        if (USE_KBF) {
            #pragma unroll
            for (int nt = 0; nt < 2; ++nt) {
                const short* kp = kbf + kTile
                    + (long long)(nbase + nt * 16 + l16) * 64 + quad * 8;
                kf[nt][0] = *(const short8*)(kp);
                kf[nt][1] = *(const short8*)(kp + 32);
            }
        } else {
            #pragma unroll
            for (int nt = 0; nt < 2; ++nt) {
                const float* kp = kfp + kTile
                    + (long long)(nbase + nt * 16 + l16) * 64 + quad * 8;
                #pragma unroll
                for (int ks = 0; ks < 2; ++ks) {
                    f4 a = *(const f4*)(kp + ks * 32);
                    f4 b = *(const f4*)(kp + ks * 32 + 4);
                    short8 f;
                    f[0] = f2bf(a.x); f[1] = f2bf(a.y); f[2] = f2bf(a.z); f[3] = f2bf(a.w);
                    f[4] = f2bf(b.x); f[5] = f2bf(b.y); f[6] = f2bf(b.z); f[7] = f2bf(b.w);
                    kf[nt][ks] = f;
                }
            }
        }

        // S^T = K @ Q^T  (C frag: row = n local = quad*4+reg, col = m = l16)
        f32x4 sf[2][4];
        #pragma unroll
        for (int nt = 0; nt < 2; ++nt)
            #pragma unroll
            for (int mt = 0; mt < 4; ++mt) sf[nt][mt] = zf;
        #pragma unroll
        for (int nt = 0; nt < 2; ++nt)
            #pragma unroll
            for (int ks = 0; ks < 2; ++ks)
                #pragma unroll
                for (int mt = 0; mt < 4; ++mt)
                    sf[nt][mt] = __builtin_amdgcn_mfma_f32_16x16x32_bf16(
                        kf[nt][ks], qf[mt][ks], sf[nt][mt], 0, 0, 0);

        // causal decay, cast bf16, store to P buffer [m][n]
        #pragma unroll
        for (int nt = 0; nt < 2; ++nt) {
            #pragma unroll
            for (int mt = 0; mt < 4; ++mt) {
                int n0 = nbase + nt * 16 + quad * 4;       // n at reg 0
                int m  = mwbase + mt * 16 + l16;
                float ddb = __expf(-slope * (float)(m - n0));
                f32x4 s = sf[nt][mt];
                float v0 = (m >= n0)     ? s[0] * ddb       : 0.f;
                float v1 = (m >= n0 + 1) ? s[1] * ddb * er1 : 0.f;
                float v2 = (m >= n0 + 2) ? s[2] * ddb * er2 : 0.f;
                float v3 = (m >= n0 + 3) ? s[3] * ddb * er3 : 0.f;
                short4v pk = {f2bf(v0), f2bf(v1), f2bf(v2), f2bf(v3)};
                *(short4v*)&P[(mt * 16 + l16) * 56 + nt * 16 + quad * 4] = pk;
            }
        }
        asm volatile("s_waitcnt lgkmcnt(0)" ::: "memory");

        // P B-fragments (B[k=n=quad*8+jj][m=l16]) — contiguous b128 reads
        short8 pb[4];
        #pragma unroll
        for (int mt = 0; mt < 4; ++mt)
            pb[mt] = *(const short8*)&P[(mt * 16 + l16) * 56 + quad * 8];

        #pragma unroll
        for (int et = 0; et < 4; ++et)
            #pragma unroll
            for (int mt = 0; mt < 4; ++mt)
                of[et][mt] = __builtin_amdgcn_mfma_f32_16x16x32_bf16(
                    va[et], pb[mt], of[et][mt], 0, 0, 0);
    }

    // ---- epilogue: O^T frag (row=e, col=m) -> out[m][e], float4 stores ----
    #pragma unroll
    for (int mt = 0; mt < 4; ++mt) {
        float* orow = out + (rowbase + mt * 16 + l16) * 64;
        #pragma unroll
        for (int et = 0; et < 4; ++et) {
            f4 o = {of[et][mt][0], of[et][mt][1], of[et][mt][2], of[et][mt][3]};
            *(f4*)(orow + et * 16 + quad * 4) = o;
        }
    }
}

// ---------------------------------------------------------------------------
extern "C" void kernel_launch(void* const* d_in, const int* in_sizes, int n_in,
                              void* d_out, int out_size, void* d_ws, size_t ws_size,
                              hipStream_t stream) {
    const float* q    = (const float*)d_in[0];
    const float* k    = (const float*)d_in[1];
    const float* v    = (const float*)d_in[2];
    const int*   mask = (const int*)d_in[3];
    float* kvt = (float*)d_ws;                                       // 32 MiB
    short* vt  = (short*)((char*)d_ws + (size_t)33554432);           // 64 MiB
    short* kbf = (short*)((char*)d_ws + (size_t)33554432 + 67108864);// 64 MiB
    float* out = (float*)d_out;

    const bool use_kbf = ws_size >= (size_t)167772160;               // 160 MiB
    if (use_kbf) {
        phase1_kvblocks<1><<<dim3(16, 128), 256, 0, stream>>>(k, v, mask, kvt, vt, kbf);
        phase2_scan<<<512, 256, 0, stream>>>(kvt);
        phase3_output<1><<<dim3(64, 128), 64, 0, stream>>>(q, k, kbf, kvt, vt, out);
    } else {
        phase1_kvblocks<0><<<dim3(16, 128), 256, 0, stream>>>(k, v, mask, kvt, vt, kbf);
        phase2_scan<<<512, 256, 0, stream>>>(kvt);
        phase3_output<0><<<dim3(64, 128), 64, 0, stream>>>(q, k, kbf, kvt, vt, out);
    }
}

// Round 2
// 518.300 us; speedup vs baseline: 1.3439x; 1.3439x over previous
//
#include <hip/hip_runtime.h>

typedef __attribute__((ext_vector_type(4))) float f4;
typedef __attribute__((ext_vector_type(4))) float f32x4;
typedef __attribute__((ext_vector_type(8))) short short8;
typedef __attribute__((ext_vector_type(4))) short short4v;

#define S_  4096
#define NB_ 16
#define SLOPE_SCALE 0.838719677419355f

__device__ __forceinline__ float slope_for_head(int h) {
    return exp2f(-(float)(h + 1) * 0.125f) * SLOPE_SCALE;
}

// fp32 -> bf16 round-to-nearest-even
__device__ __forceinline__ short f2bf(float f) {
    unsigned u = __float_as_uint(f);
    u += 0x7FFFu + ((u >> 16) & 1u);
    return (short)(u >> 16);
}
__device__ __forceinline__ float bf2f(short s) {
    return __uint_as_float(((unsigned)(unsigned short)s) << 16);
}

// ---------------------------------------------------------------------------
// Phase 1 (MFMA): per-(bh, j): KVT[e][d] = sum_n v[n][e]*kd[n]*k[n][d]
// Pipeline per 64-row stage:
//   stage fp32 (kd*k, masked v) -> convert ONCE to transposed bf16 hi/lo LDS
//   ([d][n], 144B stride = 2-way banks) -> MFMA frags are plain ds_read_b128.
// C += Vhi*Khi + Vhi*Klo + Vlo*Khi  (fp32-grade, identical math to verified r1).
// Side outputs: vt (masked V^T bf16, chunk-tiled), kbf (bf16 k, row-major).
// ---------------------------------------------------------------------------
template<int USE_KBF>
__global__ __launch_bounds__(256, 2) void phase1_kvblocks(
    const float* __restrict__ k, const float* __restrict__ v,
    const int* __restrict__ mask, float* __restrict__ kvt,
    short* __restrict__ vt, short* __restrict__ kbf)
{
    __shared__ float ks[64][64];     // kd-scaled k, [n][d]
    __shared__ float vs[64][64];     // masked v,   [n][e]
    __shared__ short khi[64][72];    // [d][n] bf16 hi
    __shared__ short klo[64][72];    // [d][n] bf16 lo
    __shared__ short vhi[64][72];    // [e][n] bf16 hi
    __shared__ short vlo[64][72];    // [e][n] bf16 lo
    const int j  = blockIdx.x;       // 0..15
    const int bh = blockIdx.y;       // 0..127
    const int b  = bh >> 6;
    const int h  = bh & 63;
    const int t  = threadIdx.x;
    const int wave = t >> 6, lane = t & 63, quad = lane >> 4, l16 = lane & 15;
    const float slope = slope_for_head(h);

    const f32x4 zf = {0.f, 0.f, 0.f, 0.f};
    f32x4 acc[4];                    // wave owns e-block = wave*16..+15; dt=0..3
    acc[0] = zf; acc[1] = zf; acc[2] = zf; acc[3] = zf;

    const long long tilebase = ((long long)bh * S_ + j * 256) * 64;
    const long long vtbase   = ((long long)(bh * NB_ + j)) * 16384;

    for (int c = 0; c < 4; ++c) {
        // ---- stage 64 rows fp32; emit kbf on the fly ----
        for (int i = 0; i < 4; ++i) {
            int fi  = t + i * 256;       // 0..1023
            int row = fi >> 4;           // 0..63
            int col = (fi & 15) << 2;    // 0..60
            long long g = tilebase + (long long)(c * 64 + row) * 64 + col;
            f4 kk = *(const f4*)(k + g);
            if (USE_KBF) {
                short4v kb = { f2bf(kk.x), f2bf(kk.y), f2bf(kk.z), f2bf(kk.w) };
                *(short4v*)(kbf + g) = kb;
            }
            float kd = __expf(-slope * (float)(255 - (c * 64 + row)));
            *(f4*)&ks[row][col] = kk * kd;
            f4 vv = *(const f4*)(v + g);
            float mv = (float)mask[b * S_ + j * 256 + c * 64 + row];
            *(f4*)&vs[row][col] = vv * mv;
        }
        __syncthreads();

        // ---- conversion pass: wave handles 16 n-rows, lane = d/e column ----
        // reads are wave-contiguous 256B (conflict-free); writes b128 at
        // 144B lane-stride (bank step 4 -> ~2-way, free).
        {
            const int dl = lane;                 // 0..63
            #pragma unroll
            for (int r = 0; r < 16; r += 8) {
                short8 k8h, k8l, v8h, v8l;
                #pragma unroll
                for (int rr = 0; rr < 8; ++rr) {
                    int n = wave * 16 + r + rr;
                    float kx = ks[n][dl];
                    short kh = f2bf(kx);
                    k8h[rr] = kh; k8l[rr] = f2bf(kx - bf2f(kh));
                    float vx = vs[n][dl];
                    short vh = f2bf(vx);
                    v8h[rr] = vh; v8l[rr] = f2bf(vx - bf2f(vh));
                }
                *(short8*)&khi[dl][wave * 16 + r] = k8h;
                *(short8*)&klo[dl][wave * 16 + r] = k8l;
                *(short8*)&vhi[dl][wave * 16 + r] = v8h;
                *(short8*)&vlo[dl][wave * 16 + r] = v8l;
            }
        }
        __syncthreads();

        // ---- V^T bf16 write (tiled layout), straight from vhi ----
        {
            int e  = t >> 2;             // 0..63
            int nb = (t & 3) << 4;       // 0,16,32,48
            short8 w0 = *(const short8*)&vhi[e][nb];
            short8 w1 = *(const short8*)&vhi[e][nb + 8];
            long long g = vtbase + (long long)(c * 2 + (nb >> 5)) * 2048
                        + e * 32 + (nb & 31);
            *(short8*)(vt + g)     = w0;
            *(short8*)(vt + g + 8) = w1;
        }

        // ---- MFMA over the 2 K=32 chunks of this stage ----
        #pragma unroll
        for (int cc = 0; cc < 2; ++cc) {
            const int nb = cc * 32 + quad * 8;
            short8 ahi = *(const short8*)&vhi[wave * 16 + l16][nb];
            short8 alo = *(const short8*)&vlo[wave * 16 + l16][nb];
            #pragma unroll
            for (int dt = 0; dt < 4; ++dt) {
                short8 bhi = *(const short8*)&khi[dt * 16 + l16][nb];
                short8 blo = *(const short8*)&klo[dt * 16 + l16][nb];
                acc[dt] = __builtin_amdgcn_mfma_f32_16x16x32_bf16(ahi, bhi, acc[dt], 0, 0, 0);
                acc[dt] = __builtin_amdgcn_mfma_f32_16x16x32_bf16(ahi, blo, acc[dt], 0, 0, 0);
                acc[dt] = __builtin_amdgcn_mfma_f32_16x16x32_bf16(alo, bhi, acc[dt], 0, 0, 0);
            }
        }
        __syncthreads();
    }

    // C frag: e = wave*16 + quad*4 + reg, d = dt*16 + l16
    float* o = kvt + ((long long)(bh * NB_ + j)) * 4096;
    #pragma unroll
    for (int dt = 0; dt < 4; ++dt) {
        #pragma unroll
        for (int r = 0; r < 4; ++r) {
            int e = wave * 16 + quad * 4 + r;
            o[e * 64 + dt * 16 + l16] = acc[dt][r];
        }
    }
}

// ---------------------------------------------------------------------------
// Phase 2: prefix scan over j. 512 blocks; all 16 tiles loaded up-front
// (independent loads -> one latency round), scan in registers, coalesced.
// ---------------------------------------------------------------------------
__global__ __launch_bounds__(256) void phase2_scan(float* __restrict__ kvt)
{
    const int g    = blockIdx.x;      // 0..511
    const int bh   = g >> 2;
    const int part = g & 3;
    const int h    = bh & 63;
    const float slope = slope_for_head(h);
    const float bd = __expf(-slope * 256.0f);

    f4* base = (f4*)(kvt + (long long)bh * NB_ * 4096) + part * 256 + threadIdx.x;
    f4 vals[NB_];
    #pragma unroll
    for (int jj = 0; jj < NB_; ++jj) vals[jj] = base[jj * 1024];
    f4 st = {0.f, 0.f, 0.f, 0.f};
    #pragma unroll
    for (int jj = 0; jj < NB_; ++jj) {
        base[jj * 1024] = st;         // S_j enters block j
        st = st * bd + vals[jj];
    }
}

// ---------------------------------------------------------------------------
// Phase 3: proven 4-wave structure (256 thr, role-balanced waves, 104 VGPR,
// no spills) + this round's deltas: kf direct from bf16 kbf (no per-chunk
// fp32->bf16 VALU), va from chunk-tiled vt (contiguous 1KB reads, and the 4
// roles in one block reuse the same kbf/vt tile through L1/L2).
// ---------------------------------------------------------------------------
template<int USE_KBF>
__global__ __launch_bounds__(256, 2) void phase3_output(
    const float* __restrict__ q, const float* __restrict__ kfp,
    const short* __restrict__ kbf, const float* __restrict__ kvt,
    const short* __restrict__ vt, float* __restrict__ out)
{
    __shared__ short P[4][64 * 56];   // per-wave [64 m][56 stride, 32 n used]
    const int j    = blockIdx.x;      // 0..15
    const int bh   = blockIdx.y;      // 0..127
    const int h    = bh & 63;
    const int tid  = threadIdx.x;
    const int wave = tid >> 6;
    const int lane = tid & 63;
    const int quad = lane >> 4;
    const int l16  = lane & 15;
    const int wrole  = (wave + j) & 3;   // balance causal trip counts across SIMDs
    const float slope = slope_for_head(h);
    const int mwbase = wrole << 6;       // wave's m base within the 256-block

    const long long rowbase = (long long)bh * S_ + j * 256 + mwbase;

    // ---- Q fragments (B-operand layout: B[k=ks*32+quad*8+jj][m=l16]) ----
    short8 qf[4][2];
    #pragma unroll
    for (int mt = 0; mt < 4; ++mt) {
        const float* qp = q + (rowbase + mt * 16 + l16) * 64 + quad * 8;
        #pragma unroll
        for (int ks = 0; ks < 2; ++ks) {
            f4 a = *(const f4*)(qp + ks * 32);
            f4 b = *(const f4*)(qp + ks * 32 + 4);
            short8 f;
            f[0] = f2bf(a.x); f[1] = f2bf(a.y); f[2] = f2bf(a.z); f[3] = f2bf(a.w);
            f[4] = f2bf(b.x); f[5] = f2bf(b.y); f[6] = f2bf(b.z); f[7] = f2bf(b.w);
            qf[mt][ks] = f;
        }
    }

    const f32x4 zf = {0.f, 0.f, 0.f, 0.f};
    f32x4 of[4][4];
    #pragma unroll
    for (int et = 0; et < 4; ++et)
        #pragma unroll
        for (int mt = 0; mt < 4; ++mt) of[et][mt] = zf;

    // ---- inter-block: O^T += kvT @ Q^T ----
    const float* kvp = kvt + ((long long)(bh * NB_ + j) << 12);
    #pragma unroll
    for (int et = 0; et < 4; ++et) {
        #pragma unroll
        for (int ks = 0; ks < 2; ++ks) {
            const float* p = kvp + (et * 16 + l16) * 64 + ks * 32 + quad * 8;
            f4 a = *(const f4*)(p);
            f4 b = *(const f4*)(p + 4);
            short8 af;
            af[0] = f2bf(a.x); af[1] = f2bf(a.y); af[2] = f2bf(a.z); af[3] = f2bf(a.w);
            af[4] = f2bf(b.x); af[5] = f2bf(b.y); af[6] = f2bf(b.z); af[7] = f2bf(b.w);
            #pragma unroll
            for (int mt = 0; mt < 4; ++mt)
                of[et][mt] = __builtin_amdgcn_mfma_f32_16x16x32_bf16(
                    af, qf[mt][ks], of[et][mt], 0, 0, 0);
        }
    }
    // scale columns (m) by q_decay[m] = exp(-slope*(m+1))
    #pragma unroll
    for (int mt = 0; mt < 4; ++mt) {
        float qd = __expf(-slope * (float)(mwbase + mt * 16 + l16 + 1));
        #pragma unroll
        for (int et = 0; et < 4; ++et) of[et][mt] *= qd;
    }

    // ---- intra-block, causal, chunks of 32 n ----
    const float er1 = __expf(slope);
    const float er2 = er1 * er1;
    const float er3 = er2 * er1;
    short* Pw = &P[wave][0];                 // index by PHYSICAL wave (privacy)
    const int nchunks = (mwbase >> 5) + 2;   // covers n < mwbase + 64
    const long long kTile = ((long long)bh * S_ + j * 256) * 64;
    const long long vTile = ((long long)(bh * NB_ + j)) * 16384;

    for (int c = 0; c < nchunks; ++c) {
        const int nbase = c << 5;

        // K A-fragments (A[n=l16][k=ks*32+quad*8+jj])
        short8 kf[2][2];
        if (USE_KBF) {
            #pragma unroll
            for (int nt = 0; nt < 2; ++nt) {
                const short* kp = kbf + kTile
                    + (long long)(nbase + nt * 16 + l16) * 64 + quad * 8;
                kf[nt][0] = *(const short8*)(kp);
                kf[nt][1] = *(const short8*)(kp + 32);
            }
        } else {
            #pragma unroll
            for (int nt = 0; nt < 2; ++nt) {
                const float* kp = kfp + kTile
                    + (long long)(nbase + nt * 16 + l16) * 64 + quad * 8;
                #pragma unroll
                for (int ks = 0; ks < 2; ++ks) {
                    f4 a = *(const f4*)(kp + ks * 32);
                    f4 b = *(const f4*)(kp + ks * 32 + 4);
                    short8 f;
                    f[0] = f2bf(a.x); f[1] = f2bf(a.y); f[2] = f2bf(a.z); f[3] = f2bf(a.w);
                    f[4] = f2bf(b.x); f[5] = f2bf(b.y); f[6] = f2bf(b.z); f[7] = f2bf(b.w);
                    kf[nt][ks] = f;
                }
            }
        }

        // S^T = K @ Q^T  (C frag: row = n local = quad*4+reg, col = m = l16)
        f32x4 sf[2][4];
        #pragma unroll
        for (int nt = 0; nt < 2; ++nt)
            #pragma unroll
            for (int mt = 0; mt < 4; ++mt) sf[nt][mt] = zf;
        #pragma unroll
        for (int nt = 0; nt < 2; ++nt)
            #pragma unroll
            for (int ks = 0; ks < 2; ++ks)
                #pragma unroll
                for (int mt = 0; mt < 4; ++mt)
                    sf[nt][mt] = __builtin_amdgcn_mfma_f32_16x16x32_bf16(
                        kf[nt][ks], qf[mt][ks], sf[nt][mt], 0, 0, 0);

        // apply causal decay, cast bf16, store to per-wave P buffer [m][n]
        #pragma unroll
        for (int nt = 0; nt < 2; ++nt) {
            #pragma unroll
            for (int mt = 0; mt < 4; ++mt) {
                int n0 = nbase + nt * 16 + quad * 4;       // n at reg 0
                int m  = mwbase + mt * 16 + l16;
                float ddb = __expf(-slope * (float)(m - n0));
                f32x4 s = sf[nt][mt];
                float v0 = (m >= n0)     ? s[0] * ddb       : 0.f;
                float v1 = (m >= n0 + 1) ? s[1] * ddb * er1 : 0.f;
                float v2 = (m >= n0 + 2) ? s[2] * ddb * er2 : 0.f;
                float v3 = (m >= n0 + 3) ? s[3] * ddb * er3 : 0.f;
                short4v pk = {f2bf(v0), f2bf(v1), f2bf(v2), f2bf(v3)};
                *(short4v*)&Pw[(mt * 16 + l16) * 56 + nt * 16 + quad * 4] = pk;
            }
        }
        asm volatile("s_waitcnt lgkmcnt(0)" ::: "memory");

        // P B-fragments (B[k=n=quad*8+jj][m=l16]) — contiguous b128 reads
        short8 pb[4];
        #pragma unroll
        for (int mt = 0; mt < 4; ++mt)
            pb[mt] = *(const short8*)&Pw[(mt * 16 + l16) * 56 + quad * 8];
        // V^T A-fragments from tiled bf16 (contiguous 1KB per et)
        short8 va[4];
        #pragma unroll
        for (int et = 0; et < 4; ++et)
            va[et] = *(const short8*)(vt + vTile + c * 2048
                                      + (et * 16 + l16) * 32 + quad * 8);

        #pragma unroll
        for (int et = 0; et < 4; ++et)
            #pragma unroll
            for (int mt = 0; mt < 4; ++mt)
                of[et][mt] = __builtin_amdgcn_mfma_f32_16x16x32_bf16(
                    va[et], pb[mt], of[et][mt], 0, 0, 0);
    }

    // ---- epilogue: O^T frag (row=e, col=m) -> out[m][e], float4 stores ----
    #pragma unroll
    for (int mt = 0; mt < 4; ++mt) {
        float* orow = out + (rowbase + mt * 16 + l16) * 64;
        #pragma unroll
        for (int et = 0; et < 4; ++et) {
            f4 o = {of[et][mt][0], of[et][mt][1], of[et][mt][2], of[et][mt][3]};
            *(f4*)(orow + et * 16 + quad * 4) = o;
        }
    }
}

// ---------------------------------------------------------------------------
extern "C" void kernel_launch(void* const* d_in, const int* in_sizes, int n_in,
                              void* d_out, int out_size, void* d_ws, size_t ws_size,
                              hipStream_t stream) {
    const float* q    = (const float*)d_in[0];
    const float* k    = (const float*)d_in[1];
    const float* v    = (const float*)d_in[2];
    const int*   mask = (const int*)d_in[3];
    float* kvt = (float*)d_ws;                                       // 32 MiB
    short* vt  = (short*)((char*)d_ws + (size_t)33554432);           // 64 MiB
    short* kbf = (short*)((char*)d_ws + (size_t)33554432 + 67108864);// 64 MiB
    float* out = (float*)d_out;

    const bool use_kbf = ws_size >= (size_t)167772160;               // 160 MiB
    if (use_kbf) {
        phase1_kvblocks<1><<<dim3(16, 128), 256, 0, stream>>>(k, v, mask, kvt, vt, kbf);
        phase2_scan<<<512, 256, 0, stream>>>(kvt);
        phase3_output<1><<<dim3(16, 128), 256, 0, stream>>>(q, k, kbf, kvt, vt, out);
    } else {
        phase1_kvblocks<0><<<dim3(16, 128), 256, 0, stream>>>(k, v, mask, kvt, vt, kbf);
        phase2_scan<<<512, 256, 0, stream>>>(kvt);
        phase3_output<0><<<dim3(16, 128), 256, 0, stream>>>(q, k, kbf, kvt, vt, out);
    }
}

// Round 3
// 496.232 us; speedup vs baseline: 1.4037x; 1.0445x over previous
//
#include <hip/hip_runtime.h>

typedef __attribute__((ext_vector_type(4))) float f4;
typedef __attribute__((ext_vector_type(4))) float f32x4;
typedef __attribute__((ext_vector_type(8))) short short8;
typedef __attribute__((ext_vector_type(4))) short short4v;

#define S_  4096
#define NB_ 16
#define SLOPE_SCALE 0.838719677419355f

__device__ __forceinline__ float slope_for_head(int h) {
    return exp2f(-(float)(h + 1) * 0.125f) * SLOPE_SCALE;
}

// fp32 -> bf16 round-to-nearest-even
__device__ __forceinline__ short f2bf(float f) {
    unsigned u = __float_as_uint(f);
    u += 0x7FFFu + ((u >> 16) & 1u);
    return (short)(u >> 16);
}
__device__ __forceinline__ float bf2f(short s) {
    return __uint_as_float(((unsigned)(unsigned short)s) << 16);
}

// XOR swizzle for [row][n32] hi/lo LDS arrays (stride 40 shorts = 20 words,
// gcd(20,32)=4 -> 8 bank groups; XOR n-block by (row>>3)&3 spreads the 8
// same-group rows over 4 word offsets -> 2-way = free).  n8 is 8-aligned.
__device__ __forceinline__ int NX(int row, int n8) {
    return n8 ^ (((row >> 3) & 3) << 3);
}

// ---------------------------------------------------------------------------
// Phase 1 (MFMA): per-(bh, j): KVT[e][d] = sum_n v[n][e]*kd[n]*k[n][d]
// 8 stages of 32 rows: reg-prefetch next stage -> stage fp32 to LDS ->
// convert once to transposed bf16 hi/lo (swizzled) -> ds_read_b128 frags.
// 36 KB LDS -> 4 blocks/CU.  C += Vhi*Khi + Vhi*Klo + Vlo*Khi.
// Side outputs: vt (masked V^T bf16, chunk-tiled), kbf (bf16 k, row-major).
// ---------------------------------------------------------------------------
template<int USE_KBF>
__global__ __launch_bounds__(256, 4) void phase1_kvblocks(
    const float* __restrict__ k, const float* __restrict__ v,
    const int* __restrict__ mask, float* __restrict__ kvt,
    short* __restrict__ vt, short* __restrict__ kbf)
{
    __shared__ float ks[32][64];     // kd-scaled k, [n][d]
    __shared__ float vs[32][64];     // masked v,   [n][e]
    __shared__ short khi[64][40];    // [d][n32] bf16 hi (swizzled)
    __shared__ short klo[64][40];
    __shared__ short vhi[64][40];    // [e][n32]
    __shared__ short vlo[64][40];
    const int j  = blockIdx.x;       // 0..15
    const int bh = blockIdx.y;       // 0..127
    const int b  = bh >> 6;
    const int h  = bh & 63;
    const int t  = threadIdx.x;
    const int wave = t >> 6, lane = t & 63, quad = lane >> 4, l16 = lane & 15;
    const float slope = slope_for_head(h);

    const f32x4 zf = {0.f, 0.f, 0.f, 0.f};
    f32x4 acc[4];                    // wave owns e-block = wave*16..+15; dt=0..3
    acc[0] = zf; acc[1] = zf; acc[2] = zf; acc[3] = zf;

    const long long tilebase = ((long long)bh * S_ + j * 256) * 64;
    const long long vtbase   = ((long long)(bh * NB_ + j)) * 16384;

    const int r0  = t >> 4;          // 0..15
    const int col = (t & 15) << 2;   // 0..60

    f4 kr0, kr1, vr0, vr1; int mr0, mr1;
    auto LOADSTG = [&](int ss) {
        long long g0 = tilebase + (long long)(ss * 32 + r0) * 64 + col;
        kr0 = *(const f4*)(k + g0);
        vr0 = *(const f4*)(v + g0);
        kr1 = *(const f4*)(k + g0 + 16 * 64);
        vr1 = *(const f4*)(v + g0 + 16 * 64);
        mr0 = mask[b * S_ + j * 256 + ss * 32 + r0];
        mr1 = mask[b * S_ + j * 256 + ss * 32 + r0 + 16];
    };
    LOADSTG(0);

    for (int ss = 0; ss < 8; ++ss) {
        // ---- write prefetched regs to LDS (+ kbf global) ----
        {
            int gn0 = ss * 32 + r0;
            if (USE_KBF) {
                long long g0 = tilebase + (long long)gn0 * 64 + col;
                short4v kb0 = { f2bf(kr0.x), f2bf(kr0.y), f2bf(kr0.z), f2bf(kr0.w) };
                short4v kb1 = { f2bf(kr1.x), f2bf(kr1.y), f2bf(kr1.z), f2bf(kr1.w) };
                *(short4v*)(kbf + g0)           = kb0;
                *(short4v*)(kbf + g0 + 16 * 64) = kb1;
            }
            float kd0 = __expf(-slope * (float)(255 - gn0));
            float kd1 = __expf(-slope * (float)(255 - gn0 - 16));
            *(f4*)&ks[r0][col]      = kr0 * kd0;
            *(f4*)&ks[r0 + 16][col] = kr1 * kd1;
            *(f4*)&vs[r0][col]      = vr0 * (float)mr0;
            *(f4*)&vs[r0 + 16][col] = vr1 * (float)mr1;
        }
        if (ss < 7) LOADSTG(ss + 1);   // latency hidden under convert+MFMA
        __syncthreads();

        // ---- convert pass: wave handles 8 n-rows, lane = d/e column ----
        {
            const int dl = lane;
            short8 k8h, k8l, v8h, v8l;
            #pragma unroll
            for (int rr = 0; rr < 8; ++rr) {
                float kx = ks[wave * 8 + rr][dl];
                short kh = f2bf(kx);
                k8h[rr] = kh; k8l[rr] = f2bf(kx - bf2f(kh));
                float vx = vs[wave * 8 + rr][dl];
                short vh = f2bf(vx);
                v8h[rr] = vh; v8l[rr] = f2bf(vx - bf2f(vh));
            }
            int ni = NX(dl, wave * 8);
            *(short8*)&khi[dl][ni] = k8h;
            *(short8*)&klo[dl][ni] = k8l;
            *(short8*)&vhi[dl][ni] = v8h;
            *(short8*)&vlo[dl][ni] = v8l;
        }
        __syncthreads();

        // ---- V^T bf16 write (tiled layout) ----
        {
            int e  = t >> 2;
            int nb = (t & 3) << 3;
            short8 w = *(const short8*)&vhi[e][NX(e, nb)];
            *(short8*)(vt + vtbase + ss * 2048 + e * 32 + nb) = w;
        }

        // ---- MFMA: one K=32 chunk per stage ----
        {
            int ar = wave * 16 + l16;
            short8 ahi = *(const short8*)&vhi[ar][NX(ar, quad * 8)];
            short8 alo = *(const short8*)&vlo[ar][NX(ar, quad * 8)];
            #pragma unroll
            for (int dt = 0; dt < 4; ++dt) {
                int br = dt * 16 + l16;
                short8 bhi = *(const short8*)&khi[br][NX(br, quad * 8)];
                short8 blo = *(const short8*)&klo[br][NX(br, quad * 8)];
                acc[dt] = __builtin_amdgcn_mfma_f32_16x16x32_bf16(ahi, bhi, acc[dt], 0, 0, 0);
                acc[dt] = __builtin_amdgcn_mfma_f32_16x16x32_bf16(ahi, blo, acc[dt], 0, 0, 0);
                acc[dt] = __builtin_amdgcn_mfma_f32_16x16x32_bf16(alo, bhi, acc[dt], 0, 0, 0);
            }
        }
        __syncthreads();
    }

    // C frag: e = wave*16 + quad*4 + reg, d = dt*16 + l16
    float* o = kvt + ((long long)(bh * NB_ + j)) * 4096;
    #pragma unroll
    for (int dt = 0; dt < 4; ++dt) {
        #pragma unroll
        for (int r = 0; r < 4; ++r) {
            int e = wave * 16 + quad * 4 + r;
            o[e * 64 + dt * 16 + l16] = acc[dt][r];
        }
    }
}

// ---------------------------------------------------------------------------
// Phase 2: prefix scan over j; optionally emits bf16 copy (kvb) of the
// per-block entering state, in the exact layout phase3's inter A-frags read.
// ---------------------------------------------------------------------------
template<int EMIT>
__global__ __launch_bounds__(256) void phase2_scan(float* __restrict__ kvt,
                                                   short* __restrict__ kvb)
{
    const int g    = blockIdx.x;      // 0..511
    const int bh   = g >> 2;
    const int part = g & 3;
    const int h    = bh & 63;
    const float slope = slope_for_head(h);
    const float bd = __expf(-slope * 256.0f);

    f4* base = (f4*)(kvt + (long long)bh * NB_ * 4096) + part * 256 + threadIdx.x;
    short* kb = kvb + (long long)bh * NB_ * 4096
              + ((long long)(part * 256 + threadIdx.x) << 2);
    f4 vals[NB_];
    #pragma unroll
    for (int jj = 0; jj < NB_; ++jj) vals[jj] = base[jj * 1024];
    f4 st = {0.f, 0.f, 0.f, 0.f};
    #pragma unroll
    for (int jj = 0; jj < NB_; ++jj) {
        base[jj * 1024] = st;         // S_j enters block j
        if (EMIT) {
            short4v sb = { f2bf(st.x), f2bf(st.y), f2bf(st.z), f2bf(st.w) };
            *(short4v*)(kb + (long long)jj * 4096) = sb;
        }
        st = st * bd + vals[jj];
    }
}

// ---------------------------------------------------------------------------
// Phase 3: 4-wave role-balanced structure, now with
//   - __launch_bounds__(256,3): ~4 blocks/CU by actual regs/LDS (was 2)
//   - kf double-buffer: chunk c+1's K frags load under chunk c's P/PV phase,
//     prologue kf0 load hidden under the inter-block section
//   - inter A-operand from pre-converted bf16 kvb (no per-use f2bf)
//   - factored causal decay: 1 exp per chunk instead of 8
// ---------------------------------------------------------------------------
template<int USE_KBF, int USE_KVB>
__global__ __launch_bounds__(256, 3) void phase3_output(
    const float* __restrict__ q, const float* __restrict__ kfp,
    const short* __restrict__ kbf, const float* __restrict__ kvt,
    const short* __restrict__ kvb, const short* __restrict__ vt,
    float* __restrict__ out)
{
    __shared__ short P[4][64 * 56];   // per-wave [64 m][56 stride, 32 n used]
    const int j    = blockIdx.x;      // 0..15
    const int bh   = blockIdx.y;      // 0..127
    const int h    = bh & 63;
    const int tid  = threadIdx.x;
    const int wave = tid >> 6;
    const int lane = tid & 63;
    const int quad = lane >> 4;
    const int l16  = lane & 15;
    const int wrole  = (wave + j) & 3;   // balance causal trip counts across SIMDs
    const float slope = slope_for_head(h);
    const int mwbase = wrole << 6;

    const long long rowbase = (long long)bh * S_ + j * 256 + mwbase;
    const long long kTile = ((long long)bh * S_ + j * 256) * 64;
    const long long vTile = ((long long)(bh * NB_ + j)) * 16384;

    // ---- Q fragments (B-operand layout: B[k=ks*32+quad*8+jj][m=l16]) ----
    short8 qf[4][2];
    #pragma unroll
    for (int mt = 0; mt < 4; ++mt) {
        const float* qp = q + (rowbase + mt * 16 + l16) * 64 + quad * 8;
        #pragma unroll
        for (int ks = 0; ks < 2; ++ks) {
            f4 a = *(const f4*)(qp + ks * 32);
            f4 b = *(const f4*)(qp + ks * 32 + 4);
            short8 f;
            f[0] = f2bf(a.x); f[1] = f2bf(a.y); f[2] = f2bf(a.z); f[3] = f2bf(a.w);
            f[4] = f2bf(b.x); f[5] = f2bf(b.y); f[6] = f2bf(b.z); f[7] = f2bf(b.w);
            qf[mt][ks] = f;
        }
    }

    auto LOADKF = [&](short8 (&dst)[2][2], int nb0) {
        #pragma unroll
        for (int nt = 0; nt < 2; ++nt) {
            const short* kp = kbf + kTile
                + (long long)(nb0 + nt * 16 + l16) * 64 + quad * 8;
            dst[nt][0] = *(const short8*)(kp);
            dst[nt][1] = *(const short8*)(kp + 32);
        }
    };

    short8 kfA[2][2];
    if (USE_KBF) LOADKF(kfA, 0);     // chunk 0; latency hides under inter

    const f32x4 zf = {0.f, 0.f, 0.f, 0.f};
    f32x4 of[4][4];
    #pragma unroll
    for (int et = 0; et < 4; ++et)
        #pragma unroll
        for (int mt = 0; mt < 4; ++mt) of[et][mt] = zf;

    // ---- inter-block: O^T += kvT @ Q^T ----
    if (USE_KVB) {
        const short* kvbp = kvb + ((long long)(bh * NB_ + j) << 12);
        #pragma unroll
        for (int et = 0; et < 4; ++et) {
            #pragma unroll
            for (int ks = 0; ks < 2; ++ks) {
                short8 af = *(const short8*)(kvbp + (et * 16 + l16) * 64
                                             + ks * 32 + quad * 8);
                #pragma unroll
                for (int mt = 0; mt < 4; ++mt)
                    of[et][mt] = __builtin_amdgcn_mfma_f32_16x16x32_bf16(
                        af, qf[mt][ks], of[et][mt], 0, 0, 0);
            }
        }
    } else {
        const float* kvp = kvt + ((long long)(bh * NB_ + j) << 12);
        #pragma unroll
        for (int et = 0; et < 4; ++et) {
            #pragma unroll
            for (int ks = 0; ks < 2; ++ks) {
                const float* p = kvp + (et * 16 + l16) * 64 + ks * 32 + quad * 8;
                f4 a = *(const f4*)(p);
                f4 b = *(const f4*)(p + 4);
                short8 af;
                af[0] = f2bf(a.x); af[1] = f2bf(a.y); af[2] = f2bf(a.z); af[3] = f2bf(a.w);
                af[4] = f2bf(b.x); af[5] = f2bf(b.y); af[6] = f2bf(b.z); af[7] = f2bf(b.w);
                #pragma unroll
                for (int mt = 0; mt < 4; ++mt)
                    of[et][mt] = __builtin_amdgcn_mfma_f32_16x16x32_bf16(
                        af, qf[mt][ks], of[et][mt], 0, 0, 0);
            }
        }
    }
    // scale columns (m) by q_decay[m] = exp(-slope*(m+1))
    #pragma unroll
    for (int mt = 0; mt < 4; ++mt) {
        float qd = __expf(-slope * (float)(mwbase + mt * 16 + l16 + 1));
        #pragma unroll
        for (int et = 0; et < 4; ++et) of[et][mt] *= qd;
    }

    // ---- intra-block, causal, chunks of 32 n ----
    const float er1 = __expf(slope);
    const float er2 = er1 * er1;
    const float er3 = er2 * er1;
    // factored decay: ddb(nt,mt,lane) = W * L * T^mt * Ti^nt
    // (product-of-exps == single exp to ~ULP; differs only where the true
    //  value is < e^-50, i.e. far below bf16 P rounding — harmless)
    const float L  = __expf(-slope * (float)(l16 - quad * 4));
    const float T1 = __expf(-slope * 16.f);
    const float Ti = __expf(slope * 16.f);
    const float Tm[4] = {1.f, T1, T1 * T1, T1 * T1 * T1};

    short* Pw = &P[wave][0];                 // index by PHYSICAL wave (privacy)
    const int nchunks = (mwbase >> 5) + 2;   // covers n < mwbase + 64

    for (int c = 0; c < nchunks; ++c) {
        const int nbase = c << 5;
        const bool havenext = (c + 1 < nchunks);

        // V^T A-fragments — issue early, used after the P phase
        short8 va[4];
        #pragma unroll
        for (int et = 0; et < 4; ++et)
            va[et] = *(const short8*)(vt + vTile + c * 2048
                                      + (et * 16 + l16) * 32 + quad * 8);

        // prefetch next chunk's K fragments (completes under P/PV below)
        short8 kfB[2][2];
        if (USE_KBF && havenext) LOADKF(kfB, nbase + 32);

        if (!USE_KBF) {
            #pragma unroll
            for (int nt = 0; nt < 2; ++nt) {
                const float* kp = kfp + kTile
                    + (long long)(nbase + nt * 16 + l16) * 64 + quad * 8;
                #pragma unroll
                for (int ks = 0; ks < 2; ++ks) {
                    f4 a = *(const f4*)(kp + ks * 32);
                    f4 b = *(const f4*)(kp + ks * 32 + 4);
                    short8 f;
                    f[0] = f2bf(a.x); f[1] = f2bf(a.y); f[2] = f2bf(a.z); f[3] = f2bf(a.w);
                    f[4] = f2bf(b.x); f[5] = f2bf(b.y); f[6] = f2bf(b.z); f[7] = f2bf(b.w);
                    kfA[nt][ks] = f;
                }
            }
        }

        // S^T = K @ Q^T  (C frag: row = n local = quad*4+reg, col = m = l16)
        f32x4 sf[2][4];
        #pragma unroll
        for (int nt = 0; nt < 2; ++nt)
            #pragma unroll
            for (int mt = 0; mt < 4; ++mt) sf[nt][mt] = zf;
        #pragma unroll
        for (int nt = 0; nt < 2; ++nt)
            #pragma unroll
            for (int ks = 0; ks < 2; ++ks)
                #pragma unroll
                for (int mt = 0; mt < 4; ++mt)
                    sf[nt][mt] = __builtin_amdgcn_mfma_f32_16x16x32_bf16(
                        kfA[nt][ks], qf[mt][ks], sf[nt][mt], 0, 0, 0);

        // apply causal decay (factored), cast bf16, store to per-wave P
        const float WL = __expf(-slope * (float)(mwbase - nbase)) * L;
        #pragma unroll
        for (int nt = 0; nt < 2; ++nt) {
            #pragma unroll
            for (int mt = 0; mt < 4; ++mt) {
                int n0 = nbase + nt * 16 + quad * 4;       // n at reg 0
                int m  = mwbase + mt * 16 + l16;
                float ddb = WL * Tm[mt];
                if (nt) ddb *= Ti;
                f32x4 s = sf[nt][mt];
                float v0 = (m >= n0)     ? s[0] * ddb       : 0.f;
                float v1 = (m >= n0 + 1) ? s[1] * ddb * er1 : 0.f;
                float v2 = (m >= n0 + 2) ? s[2] * ddb * er2 : 0.f;
                float v3 = (m >= n0 + 3) ? s[3] * ddb * er3 : 0.f;
                short4v pk = {f2bf(v0), f2bf(v1), f2bf(v2), f2bf(v3)};
                *(short4v*)&Pw[(mt * 16 + l16) * 56 + nt * 16 + quad * 4] = pk;
            }
        }
        asm volatile("s_waitcnt lgkmcnt(0)" ::: "memory");

        // P B-fragments (B[k=n=quad*8+jj][m=l16]) — contiguous b128 reads
        short8 pb[4];
        #pragma unroll
        for (int mt = 0; mt < 4; ++mt)
            pb[mt] = *(const short8*)&Pw[(mt * 16 + l16) * 56 + quad * 8];

        #pragma unroll
        for (int et = 0; et < 4; ++et)
            #pragma unroll
            for (int mt = 0; mt < 4; ++mt)
                of[et][mt] = __builtin_amdgcn_mfma_f32_16x16x32_bf16(
                    va[et], pb[mt], of[et][mt], 0, 0, 0);

        if (USE_KBF && havenext) {
            #pragma unroll
            for (int nt = 0; nt < 2; ++nt) {
                kfA[nt][0] = kfB[nt][0];
                kfA[nt][1] = kfB[nt][1];
            }
        }
    }

    // ---- epilogue: O^T frag (row=e, col=m) -> out[m][e], float4 stores ----
    #pragma unroll
    for (int mt = 0; mt < 4; ++mt) {
        float* orow = out + (rowbase + mt * 16 + l16) * 64;
        #pragma unroll
        for (int et = 0; et < 4; ++et) {
            f4 o = {of[et][mt][0], of[et][mt][1], of[et][mt][2], of[et][mt][3]};
            *(f4*)(orow + et * 16 + quad * 4) = o;
        }
    }
}

// ---------------------------------------------------------------------------
extern "C" void kernel_launch(void* const* d_in, const int* in_sizes, int n_in,
                              void* d_out, int out_size, void* d_ws, size_t ws_size,
                              hipStream_t stream) {
    const float* q    = (const float*)d_in[0];
    const float* k    = (const float*)d_in[1];
    const float* v    = (const float*)d_in[2];
    const int*   mask = (const int*)d_in[3];
    float* kvt = (float*)d_ws;                                        // 32 MiB
    short* vt  = (short*)((char*)d_ws + (size_t)33554432);            // 64 MiB
    short* kbf = (short*)((char*)d_ws + (size_t)100663296);           // 64 MiB
    short* kvb = (short*)((char*)d_ws + (size_t)167772160);           // 16 MiB
    float* out = (float*)d_out;

    if (ws_size >= (size_t)184549376) {            // kvt+vt+kbf+kvb
        phase1_kvblocks<1><<<dim3(16, 128), 256, 0, stream>>>(k, v, mask, kvt, vt, kbf);
        phase2_scan<1><<<512, 256, 0, stream>>>(kvt, kvb);
        phase3_output<1, 1><<<dim3(16, 128), 256, 0, stream>>>(q, k, kbf, kvt, kvb, vt, out);
    } else if (ws_size >= (size_t)167772160) {     // kvt+vt+kbf
        phase1_kvblocks<1><<<dim3(16, 128), 256, 0, stream>>>(k, v, mask, kvt, vt, kbf);
        phase2_scan<0><<<512, 256, 0, stream>>>(kvt, kvb);
        phase3_output<1, 0><<<dim3(16, 128), 256, 0, stream>>>(q, k, kbf, kvt, kvb, vt, out);
    } else {                                       // kvt+vt only
        phase1_kvblocks<0><<<dim3(16, 128), 256, 0, stream>>>(k, v, mask, kvt, vt, kbf);
        phase2_scan<0><<<512, 256, 0, stream>>>(kvt, kvb);
        phase3_output<0, 0><<<dim3(16, 128), 256, 0, stream>>>(q, k, kbf, kvt, kvb, vt, out);
    }
}